// Round 12
// baseline (241.151 us; speedup 1.0000x reference)
//
#include <hip/hip_runtime.h>
#include <hip/hip_cooperative_groups.h>

namespace cg = cooperative_groups;

// TenHotEncodeLayer: out[n, x[n,j]] = 1.0, rest zeros.
// B=8192 rows, NUM_TOKENS=32000 cols (f32), K=10 indices/row.
//
// R12: ONE cooperative kernel = prefetch-scatter-addresses (hidden under the
// sweep) + R7's load-free grid-stride zero sweep (unroll x4, 4MB sweeping
// window) + grid.sync() + immediate register-resident scatter.
// Removes: 2nd launch, inter-dispatch drain, cold scatter index loads.
// Lessons: R8 (no loads in sweep loop), R9 (no O(total) per block), R10
// (no extra prep dispatches), R7/R11 (dumb sweep + tiny scatter is optimal).

#define NUM_TOKENS 32000
#define KHOT 10
#define BLOCK 256
#define GRID 256                      // 1 block/CU -> coop co-residency safe
#define STRIDE (GRID * BLOCK)         // 65536 f32x4 = 1 MB per store column
#define TOTAL_F4 65536000             // 8192 * 8000
#define UNROLL 4
#define ITERS (TOTAL_F4 / (STRIDE * UNROLL))  // 250

typedef float f32x4 __attribute__((ext_vector_type(4)));
typedef int   i32x4 __attribute__((ext_vector_type(4)));

__global__ __launch_bounds__(BLOCK) void tenhot_coop(
    const int* __restrict__ x, float* __restrict__ out, int total) {
    const int t = threadIdx.x;
    const int b = blockIdx.x;

    // ---- prefetch: this block's 320 scatter entries, 4 per thread (t<80).
    // Fixed-size, statically-indexed regs (no dynamic indexing -> no scratch).
    const int per_blk = total / GRID;            // 320
    size_t addr[4];
    bool   val[4];
    {
        const int e0 = b * per_blk + 4 * t;
        const bool live = (4 * t + 3) < per_blk;  // per_blk divisible by 4
        i32x4 q = {0, 0, 0, 0};
        if (live) q = *reinterpret_cast<const i32x4*>(x + e0);
        #pragma unroll
        for (int u = 0; u < 4; ++u) {
            const int idx = q[u];
            const int e = e0 + u;
            val[u]  = live && (idx >= 0) && (idx < NUM_TOKENS);  // mode="drop"
            addr[u] = (size_t)((unsigned)e / KHOT) * NUM_TOKENS + (size_t)(unsigned)idx;
        }
    }

    // ---- sweep: load-free grid-stride zero fill, 4 stores in flight.
    f32x4* __restrict__ out4 = (f32x4*)out;
    size_t i = (size_t)b * BLOCK + t;
    const f32x4 z = {0.f, 0.f, 0.f, 0.f};
    #pragma unroll 1
    for (int k = 0; k < ITERS; ++k) {
        out4[i]              = z;
        out4[i + STRIDE]     = z;
        out4[i + 2 * STRIDE] = z;
        out4[i + 3 * STRIDE] = z;
        i += (size_t)(UNROLL * STRIDE);
    }

    // ---- grid-wide barrier replaces {drain, launch, cold start}.
    cg::this_grid().sync();

    // ---- scatter: addresses already in registers; dups/set semantics benign.
    #pragma unroll
    for (int u = 0; u < 4; ++u) {
        if (val[u]) out[addr[u]] = 1.0f;
    }
}

extern "C" void kernel_launch(void* const* d_in, const int* in_sizes, int n_in,
                              void* d_out, int out_size, void* d_ws, size_t ws_size,
                              hipStream_t stream) {
    const int* x = (const int*)d_in[0];
    float* out = (float*)d_out;
    int total = in_sizes[0];                     // 81920 = B*K
    void* args[] = {(void*)&x, (void*)&out, (void*)&total};
    hipLaunchCooperativeKernel((void*)tenhot_coop, dim3(GRID), dim3(BLOCK),
                               args, 0, stream);
}

// Round 13
// 176.540 us; speedup vs baseline: 1.3660x; 1.3660x over previous
//
#include <hip/hip_runtime.h>

// TenHotEncodeLayer: out[n, x[n,j]] = 1.0, rest zeros.
// B=8192 rows, NUM_TOKENS=32000 cols (f32), K=10 indices/row.
//
// R13 = R11 (hipMemsetAsync bulk zero at rocclr-fill speed) + RFO-FREE
// line-scatter: 8 lanes per row write each hot 128B line IN FULL (16B/lane,
// coalesced — the same store shape the fill uses, which rocprof shows fetches
// nothing). Kills the ~10MB of read-for-ownership line fills + their ~900cy
// HBM latency tail that a 4B-per-write scatter pays.
//   - lines never span rows (32000 f32 = 1000 lines exactly per row)
//   - one thread-group of 8 owns a row -> no cross-thread line conflicts
//   - first-occurrence dedup merges same-line indices; dups OR the same bit
//   - re-zeroing the line's other elements is correct (runs after the fill)
// Lessons: R8/R9/R10/R12 — all smart fused structures lose; optimize the
// dumb two-dispatch structure's tail instead.

#define NUM_TOKENS 32000
#define KHOT 10
#define BLOCK 256
#define ROWS_PER_BLOCK (BLOCK / 8)   // 32 rows per block, 8 lanes per row

typedef float f32x4 __attribute__((ext_vector_type(4)));

__global__ __launch_bounds__(BLOCK) void tenhot_scatter_lines(
    const int* __restrict__ x, float* __restrict__ out, int B) {
    const int g    = threadIdx.x >> 3;   // row-group within block (0..31)
    const int lane = threadIdx.x & 7;    // 16B slice within the 128B line
    const int row  = blockIdx.x * ROWS_PER_BLOCK + g;
    if (row >= B) return;

    // All 8 lanes of the group redundantly load the row's 10 indices
    // (wave-coherent, L1/L2 broadcast; 40B, alignment-safe scalar loads).
    int  idx[KHOT];
    bool ok [KHOT];
    int  L  [KHOT];                      // owning 128B line within the row
    #pragma unroll
    for (int j = 0; j < KHOT; ++j) {
        idx[j] = x[row * KHOT + j];
        ok[j]  = (idx[j] >= 0) && (idx[j] < NUM_TOKENS);   // mode="drop"
        L[j]   = ok[j] ? (idx[j] >> 5) : (-1 - j);         // distinct sentinels
    }

    #pragma unroll
    for (int j = 0; j < KHOT; ++j) {
        if (!ok[j]) continue;
        bool first = true;               // first occurrence of this line?
        #pragma unroll
        for (int j2 = 0; j2 < KHOT; ++j2)
            if (j2 < j && L[j2] == L[j]) first = false;
        if (!first) continue;            // line already written by earlier j

        unsigned m = 0u;                 // 32-bit hot mask for this line
        #pragma unroll
        for (int j2 = 0; j2 < KHOT; ++j2)
            if (L[j2] == L[j]) m |= 1u << (idx[j2] & 31);  // dups OR same bit

        f32x4 v;                         // my 16B slice of the line
        #pragma unroll
        for (int u = 0; u < 4; ++u)
            v[u] = ((m >> (4 * lane + u)) & 1u) ? 1.0f : 0.0f;

        // 8 lanes x 16B = one full 128B line, coalesced -> no RFO fetch.
        f32x4* dst = reinterpret_cast<f32x4*>(
            out + (size_t)row * NUM_TOKENS + (size_t)L[j] * 32);
        dst[lane] = v;
    }
}

extern "C" void kernel_launch(void* const* d_in, const int* in_sizes, int n_in,
                              void* d_out, int out_size, void* d_ws, size_t ws_size,
                              hipStream_t stream) {
    const int* x = (const int*)d_in[0];
    float* out = (float*)d_out;
    const int total = in_sizes[0];                 // 81920 = B*K
    const int B = total / KHOT;                    // 8192
    // Bulk zero at rocclr-fill speed (proven 6.8+ TB/s on this chip).
    hipMemsetAsync(d_out, 0, (size_t)out_size * sizeof(float), stream);
    // RFO-free full-line ones.
    const int grid = (B + ROWS_PER_BLOCK - 1) / ROWS_PER_BLOCK;  // 256
    tenhot_scatter_lines<<<grid, BLOCK, 0, stream>>>(x, out, B);
}